// Round 13
// baseline (201.565 us; speedup 1.0000x reference)
//
#include <hip/hip_runtime.h>
#include <hip/hip_bf16.h>

typedef unsigned short u16;
typedef unsigned int u32;
typedef __attribute__((ext_vector_type(8))) __bf16 bf16x8;
typedef __attribute__((ext_vector_type(4))) float f32x4;
typedef __attribute__((ext_vector_type(16))) float f32x16;
typedef __attribute__((ext_vector_type(4))) u32 u32x4;

#define SCL 0.18033688011112042f   // 0.125 * log2(e)

#define DEVFN static __device__ __forceinline__

DEVFN float bf2f(u16 v) { union { u32 u; float f; } x; x.u = (u32)v << 16; return x.f; }
DEVFN u16 f2bf(float f) {
    union { float f; u32 u; } x; x.f = f;
    u32 r = x.u + 0x7fff + ((x.u >> 16) & 1);
    return (u16)(r >> 16);
}

union BF2 { struct { __bf16 lo, hi; } s; u32 w; };
DEVFN u32 pk2(float a, float b) { BF2 t; t.s.lo = (__bf16)a; t.s.hi = (__bf16)b; return t.w; }

DEVFN void gload_lds16(const u16* g, u16* l) {
    __builtin_amdgcn_global_load_lds((const __attribute__((address_space(1))) u32*)g,
                                     (__attribute__((address_space(3))) u32*)l, 16, 0, 0);
}

// ---------------------------------------------------------------------------
// C = A (M,K) @ B^T (N,K), bf16 in, f32 accum. Tile 128x128, BK=32, 4 waves,
// 2-phase double-buffered LDS (stage t+1 issued before computing t; one
// vmcnt(0)+syncthreads per K-step at top of iter). R8 configuration —
// fastest measured: 49.3/49.5us on the two 32768x512x512 GEMMs.
// Staging keeps ra=tid>>2 (4 lanes x 16B = 64B row segments, coalesced);
// frag reads use foff (2.1M bank conflicts — measured nearly free; the
// R9/R10 "fix" scattered the GLOBAL pattern to 16B/transaction and lost).
// OUTMODE: 0 = bf16 C (+opt per-b f32 bias); 1 = f32 C via coalesced LDS
// epilogue (+bias, +residual f32/bf16 per RESBF); 3 = z-select (z=0: bf16
// C->Cv weights B; z=1: Vt->Cv2 weights B2).
// PERB: B and bias are per-batch (b = blockIdx.x>>5), stride 512*512 / 512.
// ---------------------------------------------------------------------------
template<int OUTMODE, bool BIAS, bool RES, bool PERB, bool RESBF>
__global__ __launch_bounds__(256)
void gemm_bt(const u16* __restrict__ A, const u16* __restrict__ B,
             const u16* __restrict__ B2,
             void* __restrict__ Cv, void* __restrict__ Cv2,
             const float* __restrict__ bias, const void* __restrict__ res,
             int K, int lda, int ldb, int ldc, float scale)
{
    __shared__ u16 smem[16384];  // 32KB: [A0 4K | B0 4K | A1 4K | B1 4K] u16
    const int tid = threadIdx.x;
    const int lane = tid & 63, wave = tid >> 6;
    const int wr = wave >> 1, wc = wave & 1;
    const u16* Bsel = (OUTMODE == 3 && blockIdx.z) ? B2 : B;
    if constexpr (PERB) Bsel += (long)(blockIdx.x >> 5) * 262144;
    const u16* Bb = Bsel + (long)blockIdx.y * 128 * ldb;
    const u16* Ab = A + (long)blockIdx.x * 128 * lda;
    const int ra = tid >> 2, ca = (tid & 3) * 8;
    const int foff = ((lane & 15) * 4 + (lane >> 4)) * 8;

    f32x4 acc[4][4];
#pragma unroll
    for (int i = 0; i < 4; ++i)
#pragma unroll
        for (int j = 0; j < 4; ++j) acc[i][j] = (f32x4){0.f, 0.f, 0.f, 0.f};

    const int nt = K >> 5;
    auto stage = [&](int t, u16* buf) {
#pragma unroll
        for (int p = 0; p < 2; ++p)
            gload_lds16(Ab + (long)(p * 64 + ra) * lda + t * 32 + ca,
                        buf + (p * 256 + tid) * 8);
#pragma unroll
        for (int p = 0; p < 2; ++p)
            gload_lds16(Bb + (long)(p * 64 + ra) * ldb + t * 32 + ca,
                        buf + 4096 + (p * 256 + tid) * 8);
    };

    stage(0, smem);
    int cur = 0;
    for (int t = 0; t < nt; ++t) {
        asm volatile("s_waitcnt vmcnt(0)" ::: "memory");
        __syncthreads();
        const int nxt = cur ^ 1;
        u16* cA = smem + cur * 8192;
        u16* cB = smem + cur * 8192 + 4096;
        if (t + 1 < nt) stage(t + 1, smem + nxt * 8192);
        bf16x8 av[4], bv[4];
#pragma unroll
        for (int i = 0; i < 4; ++i) av[i] = *(const bf16x8*)(cA + (wr * 4 + i) * 512 + foff);
#pragma unroll
        for (int j = 0; j < 4; ++j) bv[j] = *(const bf16x8*)(cB + (wc * 4 + j) * 512 + foff);
        __builtin_amdgcn_s_setprio(1);
#pragma unroll
        for (int i = 0; i < 4; ++i)
#pragma unroll
            for (int j = 0; j < 4; ++j)
                acc[i][j] = __builtin_amdgcn_mfma_f32_16x16x32_bf16(av[i], bv[j], acc[i][j], 0, 0, 0);
        __builtin_amdgcn_s_setprio(0);
        cur = nxt;
    }

    const int m0 = blockIdx.x * 128 + wr * 64 + (lane >> 4) * 4;
    const int n0 = blockIdx.y * 128 + wc * 64 + (lane & 15);
    if constexpr (OUTMODE == 0) {
        u16* Cb = (u16*)Cv;
        const float* bp = bias;
        if constexpr (PERB && BIAS) bp += (blockIdx.x >> 5) * 512;
#pragma unroll
        for (int i = 0; i < 4; ++i)
#pragma unroll
            for (int j = 0; j < 4; ++j) {
                int n = n0 + j * 16;
                float bv_ = BIAS ? bp[n] : 0.f;
#pragma unroll
                for (int r = 0; r < 4; ++r) {
                    int m = m0 + i * 16 + r;
                    Cb[(long)m * ldc + n] = f2bf(acc[i][j][r] * scale + bv_);
                }
            }
    } else if constexpr (OUTMODE == 1) {
        // coalesced f32 epilogue through padded LDS (32 x 132), 4 row-chunks
        float* cl = (float*)smem;
        float* Co = (float*)Cv;
#pragma unroll
        for (int i = 0; i < 4; ++i) {
            __syncthreads();
#pragma unroll
            for (int j = 0; j < 4; ++j)
#pragma unroll
                for (int r = 0; r < 4; ++r) {
                    int rl = wr * 16 + (lane >> 4) * 4 + r;
                    int col = wc * 64 + j * 16 + (lane & 15);
                    cl[rl * 132 + col] = acc[i][j][r];
                }
            __syncthreads();
            int rl = tid >> 3;
            int c0 = (tid & 7) * 16;
            long m = (long)blockIdx.x * 128 + i * 16 + (rl & 15) + (rl >> 4) * 64;
            long n = (long)blockIdx.y * 128 + c0;
#pragma unroll
            for (int q = 0; q < 4; ++q) {
                float4 v = *(float4*)(cl + rl * 132 + c0 + q * 4);
                float4 o;
                o.x = v.x * scale; o.y = v.y * scale;
                o.z = v.z * scale; o.w = v.w * scale;
                if constexpr (BIAS) {
                    float4 b4 = *(const float4*)(bias + n + q * 4);
                    o.x += b4.x; o.y += b4.y; o.z += b4.z; o.w += b4.w;
                }
                if constexpr (RES) {
                    if constexpr (RESBF) {
                        ushort4 r4 = *(const ushort4*)((const u16*)res + m * ldc + n + q * 4);
                        o.x += bf2f(r4.x); o.y += bf2f(r4.y);
                        o.z += bf2f(r4.z); o.w += bf2f(r4.w);
                    } else {
                        float4 r4 = *(const float4*)((const float*)res + m * ldc + n + q * 4);
                        o.x += r4.x; o.y += r4.y; o.z += r4.z; o.w += r4.w;
                    }
                }
                *(float4*)(Co + m * ldc + n + q * 4) = o;
            }
        }
    } else {  // OUTMODE == 3: z=0 bf16 C -> Cv; z=1 Vt -> Cv2
        if (blockIdx.z == 0) {
            u16* Cb = (u16*)Cv;
#pragma unroll
            for (int i = 0; i < 4; ++i)
#pragma unroll
                for (int j = 0; j < 4; ++j) {
                    int n = n0 + j * 16;
#pragma unroll
                    for (int r = 0; r < 4; ++r) {
                        int m = m0 + i * 16 + r;
                        Cb[(long)m * ldc + n] = f2bf(acc[i][j][r] * scale);
                    }
                }
        } else {
#pragma unroll
            for (int i = 0; i < 4; ++i) {
                int m = m0 + i * 16;
                int b = m >> 8, s = m & 255;
#pragma unroll
                for (int j = 0; j < 4; ++j) {
                    int n = n0 + j * 16;
                    int h = n >> 6, d = n & 63;
                    ushort4 pk;
                    pk.x = f2bf(acc[i][j][0]); pk.y = f2bf(acc[i][j][1]);
                    pk.z = f2bf(acc[i][j][2]); pk.w = f2bf(acc[i][j][3]);
                    *(ushort4*)((u16*)Cv2 + (((long)(b * 8 + h) * 64 + d) * 256 + s)) = pk;
                }
            }
        }
    }
}

// ---------------------------------------------------------------------------
// Fused attention v3 (unchanged, verified R5-R12): LDS-staged K/V + online
// softmax. grid (16, 64), 512 threads = 8 waves x 32 queries.
// ---------------------------------------------------------------------------
union U8 { u32 w[4]; bf16x8 v; };

__global__ __launch_bounds__(512, 4)
void attn_fused(const u16* __restrict__ Q, const u16* __restrict__ K,
                const u16* __restrict__ Vt, u16* __restrict__ O)
{
    __shared__ u16 lds[40960];  // 80KB
    const int tid = threadIdx.x, lane = tid & 63, wave = tid >> 6;
    const int bh = blockIdx.y, b = bh >> 3, h = bh & 7;
    const int l31 = lane & 31, lh = lane >> 5;
    const long q0 = (long)b * 4096 + blockIdx.x * 256 + wave * 32;
    const bool hiHalf = (lh != 0);

    {
        const u16* Kb_ = K + (long)b * 256 * 512 + h * 64;
        const u16* Vb_ = Vt + (long)bh * 16384;
#pragma unroll
        for (int it = 0; it < 4; ++it) {
            int f = it * 8 + wave;           // 0..31
            int st = f >> 2, kc = f & 3;
            gload_lds16(Kb_ + (long)(st * 32 + l31) * 512 + kc * 16 + lh * 8,
                        lds + f * 512 + lane * 8);
            int dt = f >> 4, ks = f & 15;
            gload_lds16(Vb_ + (long)(dt * 32 + l31) * 256 + ks * 16 + lh * 8,
                        lds + 16384 + f * 512 + lane * 8);
        }
    }
    bf16x8 qf[4];
    {
        const u16* Qp = Q + (q0 + l31) * 512 + h * 64 + lh * 8;
#pragma unroll
        for (int kc = 0; kc < 4; ++kc) qf[kc] = *(const bf16x8*)(Qp + kc * 16);
    }
    asm volatile("s_waitcnt vmcnt(0)" ::: "memory");
    __syncthreads();

    f32x16 oacc[2];
#pragma unroll
    for (int dt = 0; dt < 2; ++dt)
#pragma unroll
        for (int r = 0; r < 16; ++r) oacc[dt][r] = 0.f;
    float m_run = -3e38f, sum_run = 0.f;

#pragma unroll
    for (int st = 0; st < 8; ++st) {
        f32x16 sc;
#pragma unroll
        for (int r = 0; r < 16; ++r) sc[r] = 0.f;
        __builtin_amdgcn_s_setprio(1);
#pragma unroll
        for (int kc = 0; kc < 4; ++kc) {
            bf16x8 af = *(const bf16x8*)(lds + (st * 4 + kc) * 512 + lane * 8);
            sc = __builtin_amdgcn_mfma_f32_32x32x16_bf16(af, qf[kc], sc, 0, 0, 0);
        }
        __builtin_amdgcn_s_setprio(0);
        float tm = sc[0];
#pragma unroll
        for (int r = 1; r < 16; ++r) tm = fmaxf(tm, sc[r]);
        tm = fmaxf(tm, __shfl_xor(tm, 32));
        if (!__all(tm <= m_run + 8.f)) {
            float mnew = fmaxf(m_run, tm);
            float fac = exp2f(m_run - mnew);
            m_run = mnew;
            sum_run *= fac;
#pragma unroll
            for (int dt = 0; dt < 2; ++dt)
#pragma unroll
                for (int r = 0; r < 16; ++r) oacc[dt][r] *= fac;
        }
#pragma unroll
        for (int r = 0; r < 16; ++r) {
            float e = exp2f(sc[r] - m_run);
            sc[r] = e; sum_run += e;
        }
        u32 c[8], x[8];
#pragma unroll
        for (int i = 0; i < 8; ++i) c[i] = pk2(sc[2 * i], sc[2 * i + 1]);
#pragma unroll
        for (int i = 0; i < 8; ++i) x[i] = (u32)__shfl_xor((int)c[i], 32);
        U8 p0, p1;
        p0.w[0] = hiHalf ? x[2] : c[0];  p0.w[1] = hiHalf ? x[3] : c[1];
        p0.w[2] = hiHalf ? c[2] : x[0];  p0.w[3] = hiHalf ? c[3] : x[1];
        p1.w[0] = hiHalf ? x[6] : c[4];  p1.w[1] = hiHalf ? x[7] : c[5];
        p1.w[2] = hiHalf ? c[6] : x[4];  p1.w[3] = hiHalf ? c[7] : x[5];
        __builtin_amdgcn_s_setprio(1);
#pragma unroll
        for (int dt = 0; dt < 2; ++dt) {
            bf16x8 v0 = *(const bf16x8*)(lds + 16384 + (dt * 16 + st * 2) * 512 + lane * 8);
            bf16x8 v1 = *(const bf16x8*)(lds + 16384 + (dt * 16 + st * 2 + 1) * 512 + lane * 8);
            oacc[dt] = __builtin_amdgcn_mfma_f32_32x32x16_bf16(v0, p0.v, oacc[dt], 0, 0, 0);
            oacc[dt] = __builtin_amdgcn_mfma_f32_32x32x16_bf16(v1, p1.v, oacc[dt], 0, 0, 0);
        }
        __builtin_amdgcn_s_setprio(0);
    }

    sum_run += __shfl_xor(sum_run, 32);
    float inv = 1.f / sum_run;

    u16* ow = lds + 32768 + (wave & 3) * 2048;
    const int shift = wave >> 2;
#pragma unroll
    for (int s_ = 0; s_ < 2; ++s_) {
        if (s_ == 1) __syncthreads();
        if (shift == s_) {
            const int q = l31;
#pragma unroll
            for (int dt = 0; dt < 2; ++dt)
#pragma unroll
                for (int rq = 0; rq < 4; ++rq) {
                    int d = dt * 32 + rq * 8 + 4 * lh;
                    u32 w0 = pk2(oacc[dt][rq * 4 + 0] * inv, oacc[dt][rq * 4 + 1] * inv);
                    u32 w1 = pk2(oacc[dt][rq * 4 + 2] * inv, oacc[dt][rq * 4 + 3] * inv);
                    int byte = q * 128 + ((d * 2) ^ ((q & 7) << 4));
                    *(u32*)((char*)ow + byte) = w0;
                    *(u32*)((char*)ow + byte + 4) = w1;
                }
#pragma unroll
            for (int i = 0; i < 4; ++i) {
                int qq = (lane >> 3) + i * 8;
                int byte = qq * 128 + (((lane & 7) * 16) ^ ((qq & 7) << 4));
                bf16x8 val = *(const bf16x8*)((char*)ow + byte);
                *(bf16x8*)(O + (q0 + qq) * 512 + h * 64 + (lane & 7) * 8) = val;
            }
        }
    }
}

// ---------------------------------------------------------------------------
// GroupNorm partials + free bf16(x) emission (reads all of x anyway).
// ---------------------------------------------------------------------------
__global__ __launch_bounds__(256)
void gn_part(const float* __restrict__ x, float* __restrict__ part,
             u16* __restrict__ xb)
{
    const int b = blockIdx.x, ch = blockIdx.y;
    const long base = ((long)b * 4096 + ch * 64) * 512;
    const float* bx = x + base;
    u16* bo = xb + base;
    const int t = threadIdx.x;
    const int c4 = t & 127, r0 = t >> 7;
    float sum = 0.f, sq = 0.f;
    for (int rr = r0; rr < 64; rr += 2) {
        float4 v = *(const float4*)(bx + (long)rr * 512 + c4 * 4);
        sum += v.x + v.y + v.z + v.w;
        sq  += v.x * v.x + v.y * v.y + v.z * v.z + v.w * v.w;
        uint2 w;
        w.x = pk2(v.x, v.y); w.y = pk2(v.z, v.w);
        *(uint2*)(bo + (long)rr * 512 + c4 * 4) = w;
    }
    __shared__ float s0[128], s1[128];
    if (t >= 128) { s0[c4] = sum; s1[c4] = sq; }
    __syncthreads();
    if (t < 128) {
        sum += s0[c4]; sq += s1[c4];
        sum += __shfl_down(sum, 2); sum += __shfl_down(sum, 1);
        sq  += __shfl_down(sq, 2);  sq  += __shfl_down(sq, 1);
        if ((t & 3) == 0) {
            int g = t >> 2;
            float* pp = part + (long)(b * 64 + ch) * 64;
            pp[g] = sum; pp[32 + g] = sq;
        }
    }
}

__global__ __launch_bounds__(256)
void gn_coef(const float* __restrict__ part, const float* __restrict__ gscale,
             const float* __restrict__ gbias, float* __restrict__ coefA,
             float* __restrict__ coefD)
{
    const int t = threadIdx.x;
    const int b = t >> 5, g = t & 31;
    float S = 0.f, Q = 0.f;
    for (int ch = 0; ch < 64; ++ch) {
        const float* pp = part + (long)(b * 64 + ch) * 64;
        S += pp[g]; Q += pp[32 + g];
    }
    float mean = S * (1.f / 65536.f);
    float var = Q * (1.f / 65536.f) - mean * mean;
    float rstd = rsqrtf(var + 1e-5f);
#pragma unroll
    for (int cc = 0; cc < 16; ++cc) {
        int c = g * 16 + cc;
        float a = gscale[c] * rstd;
        coefA[b * 512 + c] = a;
        coefD[b * 512 + c] = gbias[c] - mean * a;
    }
}

// per-batch scaled+transposed Q weights: WqS[b][n][c] = bf16(SCL*a[b][c]*Wq[c][n])
__global__ __launch_bounds__(256)
void scale_wq(const float* __restrict__ Wq, const float* __restrict__ cfA,
              u16* __restrict__ WqS)
{
    __shared__ u16 t[32][33];
    const int b = blockIdx.z;
    const int r0 = blockIdx.y * 32, c0 = blockIdx.x * 32;  // r0: c-dim, c0: n-dim
    int tx = threadIdx.x & 31, ty = threadIdx.x >> 5;
    for (int i = ty; i < 32; i += 8)
        t[i][tx] = f2bf(Wq[(long)(r0 + i) * 512 + c0 + tx] * cfA[b * 512 + r0 + i] * SCL);
    __syncthreads();
    for (int i = ty; i < 32; i += 8)
        WqS[(long)b * 262144 + (long)(c0 + i) * 512 + r0 + tx] = t[tx][i];
}

// dq[b][n] = SCL * sum_c cfD[b][c] * Wq[c][n]  — grid (8 b, 8 n-chunks)
__global__ __launch_bounds__(256)
void dq_bias(const float* __restrict__ Wq, const float* __restrict__ cfD,
             float* __restrict__ dq)
{
    const int b = blockIdx.x, nc = blockIdx.y;
    const int t = threadIdx.x;
    const int n = nc * 64 + (t & 63);
    const int cq = t >> 6;            // 4 c-quarters of 128
    float a = 0.f;
    for (int c = cq * 128; c < cq * 128 + 128; ++c)
        a += cfD[b * 512 + c] * Wq[(long)c * 512 + n];
    __shared__ float red[256];
    red[t] = a;
    __syncthreads();
    if (t < 64) {
        float s = red[t] + red[64 + t] + red[128 + t] + red[192 + t];
        dq[b * 512 + nc * 64 + t] = s * SCL;
    }
}

// f32 -> bf16 bulk convert (n multiple of 8*256)
__global__ __launch_bounds__(256)
void conv_bf16(const float* __restrict__ in, u16* __restrict__ out)
{
    long e = ((long)blockIdx.x * 256 + threadIdx.x) * 8;
    float4 v0 = *(const float4*)(in + e);
    float4 v1 = *(const float4*)(in + e + 4);
    float f[8] = { v0.x, v0.y, v0.z, v0.w, v1.x, v1.y, v1.z, v1.w };
    u32x4 o;
#pragma unroll
    for (int q = 0; q < 4; ++q)
        o[q] = (u32)f2bf(f[q * 2]) | ((u32)f2bf(f[q * 2 + 1]) << 16);
    *(u32x4*)(out + e) = o;
}

// weight transposes (f32 -> bf16): z = 0 Wk(768), 1 Wv(768), 2 Wo(512)
__global__ __launch_bounds__(256)
void transpose_all(const float* __restrict__ Wk, const float* __restrict__ Wv,
                   const float* __restrict__ Wo,
                   u16* __restrict__ WkT, u16* __restrict__ WvT,
                   u16* __restrict__ WoT)
{
    __shared__ u16 t[32][33];
    const int z = blockIdx.z;
    const float* in = (z == 0) ? Wk : (z == 1) ? Wv : Wo;
    u16* out = (z == 0) ? WkT : (z == 1) ? WvT : WoT;
    const int R = (z < 2) ? 768 : 512, C = 512;
    const int r0 = blockIdx.y * 32, c0 = blockIdx.x * 32;
    if (r0 >= R) return;
    int tx = threadIdx.x & 31, ty = threadIdx.x >> 5;
    for (int i = ty; i < 32; i += 8) t[i][tx] = f2bf(in[(long)(r0 + i) * C + c0 + tx]);
    __syncthreads();
    for (int i = ty; i < 32; i += 8) out[(long)(c0 + i) * R + r0 + tx] = t[tx][i];
}

extern "C" void kernel_launch(void* const* d_in, const int* in_sizes, int n_in,
                              void* d_out, int out_size, void* d_ws, size_t ws_size,
                              hipStream_t stream)
{
    const float* x    = (const float*)d_in[0];
    const float* cond = (const float*)d_in[1];
    const float* gsc  = (const float*)d_in[2];
    const float* gbi  = (const float*)d_in[3];
    const float* Wq   = (const float*)d_in[4];
    const float* Wk   = (const float*)d_in[5];
    const float* Wv   = (const float*)d_in[6];
    const float* Wo   = (const float*)d_in[7];
    const float* bo   = (const float*)d_in[8];

    char* ws = (char*)d_ws;
    size_t off = 0;
    auto alloc = [&](size_t bytes) -> void* {
        void* p = ws + off; off += (bytes + 255) & ~(size_t)255; return p;
    };
    u16* WkT    = (u16*)alloc(512 * 768 * 2);
    u16* WvT    = (u16*)alloc(512 * 768 * 2);
    u16* WoT    = (u16*)alloc(512 * 512 * 2);
    u16* WqS    = (u16*)alloc(8l * 512 * 512 * 2);   // per-batch scaled Wq^T
    float* cfA  = (float*)alloc(8 * 512 * 4);
    float* cfD  = (float*)alloc(8 * 512 * 4);
    float* dq   = (float*)alloc(8 * 512 * 4);
    float* part = (float*)alloc(8 * 64 * 64 * 4);
    u16* condb  = (u16*)alloc(2048l * 768 * 2);
    u16* xb     = (u16*)alloc(33554432);   // bf16(x)
    u16* Ob     = (u16*)alloc(33554432);
    u16* Qb     = (u16*)alloc(33554432);
    u16* Kb     = (u16*)alloc(2048l * 512 * 2);
    u16* Vt     = (u16*)alloc(2097152);

    transpose_all<<<dim3(16, 24, 3), 256, 0, stream>>>(Wk, Wv, Wo, WkT, WvT, WoT);
    conv_bf16<<<768, 256, 0, stream>>>(cond, condb);

    gn_part<<<dim3(8, 64), 256, 0, stream>>>(x, part, xb);
    gn_coef<<<1, 256, 0, stream>>>(part, gsc, gbi, cfA, cfD);
    scale_wq<<<dim3(16, 16, 8), 256, 0, stream>>>(Wq, cfA, WqS);
    dq_bias<<<dim3(8, 8), 256, 0, stream>>>(Wq, cfD, dq);

    // K and V in one launch (z=0: K->Kb; z=1: V->Vt transposed per head)
    gemm_bt<3, false, false, false, false><<<dim3(16, 4, 2), 256, 0, stream>>>(
        condb, WkT, WvT, Kb, Vt, nullptr, nullptr, 768, 768, 768, 512, 1.f);

    // Q = xb @ WqS[b]^T + dq[b]   (GN affine folded into weights/bias)
    gemm_bt<0, true, false, true, false><<<dim3(256, 4), 256, 0, stream>>>(
        xb, WqS, nullptr, Qb, nullptr, dq, nullptr, 512, 512, 512, 512, 1.f);

    // fused attention: scores+softmax+PV, writes Ob
    attn_fused<<<dim3(16, 64), 512, 0, stream>>>(Qb, Kb, Vt, Ob);

    // out = xb + Ob @ WoT + bo    (32768 x 512 x 512), f32, coalesced epilogue
    gemm_bt<1, true, true, false, true><<<dim3(256, 4), 256, 0, stream>>>(
        Ob, WoT, nullptr, d_out, nullptr, bo, xb, 512, 512, 512, 512, 1.f);
}

// Round 14
// 201.435 us; speedup vs baseline: 1.0006x; 1.0006x over previous
//
#include <hip/hip_runtime.h>
#include <hip/hip_bf16.h>

typedef unsigned short u16;
typedef unsigned int u32;
typedef __attribute__((ext_vector_type(8))) __bf16 bf16x8;
typedef __attribute__((ext_vector_type(4))) float f32x4;
typedef __attribute__((ext_vector_type(16))) float f32x16;
typedef __attribute__((ext_vector_type(4))) u32 u32x4;

#define DEVFN static __device__ __forceinline__

DEVFN float bf2f(u16 v) { union { u32 u; float f; } x; x.u = (u32)v << 16; return x.f; }
DEVFN u16 f2bf(float f) {
    union { float f; u32 u; } x; x.f = f;
    u32 r = x.u + 0x7fff + ((x.u >> 16) & 1);
    return (u16)(r >> 16);
}

union BF2 { struct { __bf16 lo, hi; } s; u32 w; };
DEVFN u32 pk2(float a, float b) { BF2 t; t.s.lo = (__bf16)a; t.s.hi = (__bf16)b; return t.w; }

DEVFN void gload_lds16(const u16* g, u16* l) {
    __builtin_amdgcn_global_load_lds((const __attribute__((address_space(1))) u32*)g,
                                     (__attribute__((address_space(3))) u32*)l, 16, 0, 0);
}

// ---------------------------------------------------------------------------
// C = A (M,K) @ B^T (N,K), bf16 in, f32 accum. Tile 128x128, BK=32, 4 waves.
// Non-AFF path: R7/R11 loop (vmcnt(0)+__syncthreads per K-step) — measured
// best for out-proj / K/V. AFF path (Q only): depth-2 x-prefetch —
// affLoad(t+2) issued at iter t, consumed at end of iter t+1; raw s_barrier
// with counted "vmcnt(4) lgkmcnt(0)" so the prefetch survives the barrier
// (oldest 2 VM ops = stageB(t), pinned by asm memory clobbers). Coefs
// (block-constant, 4KB) preloaded to LDS (R12) to keep VGPR ~96.
// OUTMODE: 0 = bf16 C; 1 = f32 C via coalesced LDS epilogue (+bias/residual);
// 3 = z-select (z=0: bf16 C->Cv weights B, z=1: Vt->Cv2 weights B2).
// ---------------------------------------------------------------------------
template<int OUTMODE, bool BIAS, bool RES, bool AFF>
__global__ __launch_bounds__(256)
void gemm_bt(const void* __restrict__ Av, const u16* __restrict__ B,
             const u16* __restrict__ B2,
             void* __restrict__ Cv, void* __restrict__ Cv2,
             const float* __restrict__ bias, const float* __restrict__ res,
             const float* __restrict__ cfA, const float* __restrict__ cfD,
             int K, int lda, int ldb, int ldc, float scale)
{
    __shared__ u16 smem[AFF ? 18432 : 16384];  // +4KB coef region when AFF
    const int tid = threadIdx.x;
    const int lane = tid & 63, wave = tid >> 6;
    const int wr = wave >> 1, wc = wave & 1;
    const u16* Bsel = (OUTMODE == 3 && blockIdx.z) ? B2 : B;
    const u16* Bb = Bsel + (long)blockIdx.y * 128 * ldb;
    const int ra = tid >> 2, ca = (tid & 3) * 8;       // staging row/col in pass
    const int foff = ((lane & 15) * 4 + (lane >> 4)) * 8;

    f32x4 acc[4][4];
#pragma unroll
    for (int i = 0; i < 4; ++i)
#pragma unroll
        for (int j = 0; j < 4; ++j) acc[i][j] = (f32x4){0.f, 0.f, 0.f, 0.f};

    const int nt = K >> 5;

    auto stageB = [&](int t, u16* bb) {
#pragma unroll
        for (int p = 0; p < 2; ++p)
            gload_lds16(Bb + (long)(p * 64 + ra) * ldb + t * 32 + ca,
                        bb + (p * 256 + tid) * 8);
    };
    const u16* Ab = (const u16*)Av + (long)blockIdx.x * 128 * lda;
    auto stageA = [&](int t, u16* ab) {
#pragma unroll
        for (int p = 0; p < 2; ++p)
            gload_lds16(Ab + (long)(p * 64 + ra) * lda + t * 32 + ca,
                        ab + (p * 256 + tid) * 8);
    };
    const float* xf = (const float*)Av;
    auto affLoad = [&](int t, float4 (&xr)[2][2]) {
#pragma unroll
        for (int p = 0; p < 2; ++p) {
            long m = (long)blockIdx.x * 128 + p * 64 + ra;
            int c = t * 32 + ca;
            const float* src = xf + m * lda + c;
            xr[p][0] = *(const float4*)(src);
            xr[p][1] = *(const float4*)(src + 4);
        }
    };
    auto affWrite = [&](int t, float4 (&xr)[2][2], u16* ab) {
        float* ldsCA = (float*)(smem + 16384);
        float* ldsCD = ldsCA + 512;
        int c = t * 32 + ca;
        float4 a0 = *(const float4*)(ldsCA + c);
        float4 a1 = *(const float4*)(ldsCA + c + 4);
        float4 d0 = *(const float4*)(ldsCD + c);
        float4 d1 = *(const float4*)(ldsCD + c + 4);
#pragma unroll
        for (int p = 0; p < 2; ++p) {
            u32x4 o;
            o[0] = pk2(xr[p][0].x * a0.x + d0.x, xr[p][0].y * a0.y + d0.y);
            o[1] = pk2(xr[p][0].z * a0.z + d0.z, xr[p][0].w * a0.w + d0.w);
            o[2] = pk2(xr[p][1].x * a1.x + d1.x, xr[p][1].y * a1.y + d1.y);
            o[3] = pk2(xr[p][1].z * a1.z + d1.z, xr[p][1].w * a1.w + d1.w);
            *(u32x4*)(ab + (p * 256 + tid) * 8) = o;
        }
    };

    if constexpr (AFF) {
        // preload this block's batch coefs (block-constant) into LDS once
        {
            float* ldsCA = (float*)(smem + 16384);
            float* ldsCD = ldsCA + 512;
            int cb0 = (int)((((long)blockIdx.x * 128) >> 12) << 9);  // batch*512
            float2 a2 = *(const float2*)(cfA + cb0 + tid * 2);
            float2 d2 = *(const float2*)(cfD + cb0 + tid * 2);
            *(float2*)(ldsCA + tid * 2) = a2;
            *(float2*)(ldsCD + tid * 2) = d2;
            __syncthreads();
        }
        float4 xr0[2][2], xr1[2][2];
        // prologue: tile0 fully staged; tile1 B-stage + x-prefetch issued
        stageB(0, smem + 4096);
        affLoad(0, xr0);
        affWrite(0, xr0, smem);
        stageB(1, smem + 8192 + 4096);
        affLoad(1, xr1);

        auto bodyA = [&](int t, u16* cbuf, u16* nbuf,
                         float4 (&xrC)[2][2], float4 (&xrL)[2][2]) {
            if (t + 1 < nt) asm volatile("s_waitcnt vmcnt(4) lgkmcnt(0)" ::: "memory");
            else            asm volatile("s_waitcnt vmcnt(0) lgkmcnt(0)" ::: "memory");
            __builtin_amdgcn_s_barrier();
            asm volatile("" ::: "memory");
            if (t + 1 < nt) stageB(t + 1, nbuf + 4096);
            asm volatile("" ::: "memory");      // pin: stageB older than affLoad
            if (t + 2 < nt) affLoad(t + 2, xrL);
            asm volatile("" ::: "memory");
            bf16x8 av[4], bv[4];
#pragma unroll
            for (int i = 0; i < 4; ++i) av[i] = *(const bf16x8*)(cbuf + (wr * 4 + i) * 512 + foff);
#pragma unroll
            for (int j = 0; j < 4; ++j) bv[j] = *(const bf16x8*)(cbuf + 4096 + (wc * 4 + j) * 512 + foff);
            __builtin_amdgcn_s_setprio(1);
#pragma unroll
            for (int i = 0; i < 4; ++i)
#pragma unroll
                for (int j = 0; j < 4; ++j)
                    acc[i][j] = __builtin_amdgcn_mfma_f32_16x16x32_bf16(av[i], bv[j], acc[i][j], 0, 0, 0);
            __builtin_amdgcn_s_setprio(0);
            if (t + 1 < nt) affWrite(t + 1, xrC, nbuf);   // write-late (T14)
        };
        for (int t = 0; t < nt; t += 2) {                 // nt even (K=512)
            bodyA(t,     smem,        smem + 8192, xr1, xr0);
            bodyA(t + 1, smem + 8192, smem,        xr0, xr1);
        }
    } else {
        // ---- R7/R11 loop, byte-identical
        stageB(0, smem + 4096);
        stageA(0, smem);
        int cur = 0;
        for (int t = 0; t < nt; ++t) {
            asm volatile("s_waitcnt vmcnt(0)" ::: "memory");
            __syncthreads();
            const int nxt = cur ^ 1;
            u16* cA = smem + cur * 8192;
            u16* cB = smem + cur * 8192 + 4096;
            u16* nA = smem + nxt * 8192;
            u16* nB = smem + nxt * 8192 + 4096;
            if (t + 1 < nt) {
                stageB(t + 1, nB);
                stageA(t + 1, nA);
            }
            bf16x8 av[4], bv[4];
#pragma unroll
            for (int i = 0; i < 4; ++i) av[i] = *(const bf16x8*)(cA + (wr * 4 + i) * 512 + foff);
#pragma unroll
            for (int j = 0; j < 4; ++j) bv[j] = *(const bf16x8*)(cB + (wc * 4 + j) * 512 + foff);
            __builtin_amdgcn_s_setprio(1);
#pragma unroll
            for (int i = 0; i < 4; ++i)
#pragma unroll
                for (int j = 0; j < 4; ++j)
                    acc[i][j] = __builtin_amdgcn_mfma_f32_16x16x32_bf16(av[i], bv[j], acc[i][j], 0, 0, 0);
            __builtin_amdgcn_s_setprio(0);
            cur = nxt;
        }
    }

    const int m0 = blockIdx.x * 128 + wr * 64 + (lane >> 4) * 4;
    const int n0 = blockIdx.y * 128 + wc * 64 + (lane & 15);
    if constexpr (OUTMODE == 0) {
        u16* Cb = (u16*)Cv;
#pragma unroll
        for (int i = 0; i < 4; ++i)
#pragma unroll
            for (int j = 0; j < 4; ++j) {
                int n = n0 + j * 16;
#pragma unroll
                for (int r = 0; r < 4; ++r) {
                    int m = m0 + i * 16 + r;
                    Cb[(long)m * ldc + n] = f2bf(acc[i][j][r] * scale);
                }
            }
    } else if constexpr (OUTMODE == 1) {
        // coalesced f32 epilogue through padded LDS (32 x 132), 4 row-chunks
        float* cl = (float*)smem;
        float* Co = (float*)Cv;
#pragma unroll
        for (int i = 0; i < 4; ++i) {
            __syncthreads();
#pragma unroll
            for (int j = 0; j < 4; ++j)
#pragma unroll
                for (int r = 0; r < 4; ++r) {
                    int rl = wr * 16 + (lane >> 4) * 4 + r;
                    int col = wc * 64 + j * 16 + (lane & 15);
                    cl[rl * 132 + col] = acc[i][j][r];
                }
            __syncthreads();
            int rl = tid >> 3;
            int c0 = (tid & 7) * 16;
            long m = (long)blockIdx.x * 128 + i * 16 + (rl & 15) + (rl >> 4) * 64;
            long n = (long)blockIdx.y * 128 + c0;
#pragma unroll
            for (int q = 0; q < 4; ++q) {
                float4 v = *(float4*)(cl + rl * 132 + c0 + q * 4);
                float4 o;
                o.x = v.x * scale; o.y = v.y * scale;
                o.z = v.z * scale; o.w = v.w * scale;
                if constexpr (BIAS) {
                    float4 b4 = *(const float4*)(bias + n + q * 4);
                    o.x += b4.x; o.y += b4.y; o.z += b4.z; o.w += b4.w;
                }
                if constexpr (RES) {
                    float4 r4 = *(const float4*)(res + m * ldc + n + q * 4);
                    o.x += r4.x; o.y += r4.y; o.z += r4.z; o.w += r4.w;
                }
                *(float4*)(Co + m * ldc + n + q * 4) = o;
            }
        }
    } else {  // OUTMODE == 3: z=0 bf16 C -> Cv; z=1 Vt -> Cv2
        if (blockIdx.z == 0) {
            u16* Cb = (u16*)Cv;
#pragma unroll
            for (int i = 0; i < 4; ++i)
#pragma unroll
                for (int j = 0; j < 4; ++j) {
                    int n = n0 + j * 16;
#pragma unroll
                    for (int r = 0; r < 4; ++r) {
                        int m = m0 + i * 16 + r;
                        Cb[(long)m * ldc + n] = f2bf(acc[i][j][r] * scale);
                    }
                }
        } else {
#pragma unroll
            for (int i = 0; i < 4; ++i) {
                int m = m0 + i * 16;
                int b = m >> 8, s = m & 255;
#pragma unroll
                for (int j = 0; j < 4; ++j) {
                    int n = n0 + j * 16;
                    int h = n >> 6, d = n & 63;
                    ushort4 pk;
                    pk.x = f2bf(acc[i][j][0]); pk.y = f2bf(acc[i][j][1]);
                    pk.z = f2bf(acc[i][j][2]); pk.w = f2bf(acc[i][j][3]);
                    *(ushort4*)((u16*)Cv2 + (((long)(b * 8 + h) * 64 + d) * 256 + s)) = pk;
                }
            }
        }
    }
}

// ---------------------------------------------------------------------------
// Fused attention v3 (unchanged, verified R5-R13): LDS-staged K/V + online
// softmax. grid (16, 64), 512 threads = 8 waves x 32 queries.
// ---------------------------------------------------------------------------
union U8 { u32 w[4]; bf16x8 v; };

__global__ __launch_bounds__(512, 4)
void attn_fused(const u16* __restrict__ Q, const u16* __restrict__ K,
                const u16* __restrict__ Vt, u16* __restrict__ O)
{
    __shared__ u16 lds[40960];  // 80KB
    const int tid = threadIdx.x, lane = tid & 63, wave = tid >> 6;
    const int bh = blockIdx.y, b = bh >> 3, h = bh & 7;
    const int l31 = lane & 31, lh = lane >> 5;
    const long q0 = (long)b * 4096 + blockIdx.x * 256 + wave * 32;
    const bool hiHalf = (lh != 0);

    {
        const u16* Kb_ = K + (long)b * 256 * 512 + h * 64;
        const u16* Vb_ = Vt + (long)bh * 16384;
#pragma unroll
        for (int it = 0; it < 4; ++it) {
            int f = it * 8 + wave;           // 0..31
            int st = f >> 2, kc = f & 3;
            gload_lds16(Kb_ + (long)(st * 32 + l31) * 512 + kc * 16 + lh * 8,
                        lds + f * 512 + lane * 8);
            int dt = f >> 4, ks = f & 15;
            gload_lds16(Vb_ + (long)(dt * 32 + l31) * 256 + ks * 16 + lh * 8,
                        lds + 16384 + f * 512 + lane * 8);
        }
    }
    bf16x8 qf[4];
    {
        const u16* Qp = Q + (q0 + l31) * 512 + h * 64 + lh * 8;
#pragma unroll
        for (int kc = 0; kc < 4; ++kc) qf[kc] = *(const bf16x8*)(Qp + kc * 16);
    }
    asm volatile("s_waitcnt vmcnt(0)" ::: "memory");
    __syncthreads();

    f32x16 oacc[2];
#pragma unroll
    for (int dt = 0; dt < 2; ++dt)
#pragma unroll
        for (int r = 0; r < 16; ++r) oacc[dt][r] = 0.f;
    float m_run = -3e38f, sum_run = 0.f;

#pragma unroll
    for (int st = 0; st < 8; ++st) {
        f32x16 sc;
#pragma unroll
        for (int r = 0; r < 16; ++r) sc[r] = 0.f;
        __builtin_amdgcn_s_setprio(1);
#pragma unroll
        for (int kc = 0; kc < 4; ++kc) {
            bf16x8 af = *(const bf16x8*)(lds + (st * 4 + kc) * 512 + lane * 8);
            sc = __builtin_amdgcn_mfma_f32_32x32x16_bf16(af, qf[kc], sc, 0, 0, 0);
        }
        __builtin_amdgcn_s_setprio(0);
        float tm = sc[0];
#pragma unroll
        for (int r = 1; r < 16; ++r) tm = fmaxf(tm, sc[r]);
        tm = fmaxf(tm, __shfl_xor(tm, 32));
        if (!__all(tm <= m_run + 8.f)) {
            float mnew = fmaxf(m_run, tm);
            float fac = exp2f(m_run - mnew);
            m_run = mnew;
            sum_run *= fac;
#pragma unroll
            for (int dt = 0; dt < 2; ++dt)
#pragma unroll
                for (int r = 0; r < 16; ++r) oacc[dt][r] *= fac;
        }
#pragma unroll
        for (int r = 0; r < 16; ++r) {
            float e = exp2f(sc[r] - m_run);
            sc[r] = e; sum_run += e;
        }
        u32 c[8], x[8];
#pragma unroll
        for (int i = 0; i < 8; ++i) c[i] = pk2(sc[2 * i], sc[2 * i + 1]);
#pragma unroll
        for (int i = 0; i < 8; ++i) x[i] = (u32)__shfl_xor((int)c[i], 32);
        U8 p0, p1;
        p0.w[0] = hiHalf ? x[2] : c[0];  p0.w[1] = hiHalf ? x[3] : c[1];
        p0.w[2] = hiHalf ? c[2] : x[0];  p0.w[3] = hiHalf ? c[3] : x[1];
        p1.w[0] = hiHalf ? x[6] : c[4];  p1.w[1] = hiHalf ? x[7] : c[5];
        p1.w[2] = hiHalf ? c[6] : x[4];  p1.w[3] = hiHalf ? c[7] : x[5];
        __builtin_amdgcn_s_setprio(1);
#pragma unroll
        for (int dt = 0; dt < 2; ++dt) {
            bf16x8 v0 = *(const bf16x8*)(lds + 16384 + (dt * 16 + st * 2) * 512 + lane * 8);
            bf16x8 v1 = *(const bf16x8*)(lds + 16384 + (dt * 16 + st * 2 + 1) * 512 + lane * 8);
            oacc[dt] = __builtin_amdgcn_mfma_f32_32x32x16_bf16(v0, p0.v, oacc[dt], 0, 0, 0);
            oacc[dt] = __builtin_amdgcn_mfma_f32_32x32x16_bf16(v1, p1.v, oacc[dt], 0, 0, 0);
        }
        __builtin_amdgcn_s_setprio(0);
    }

    sum_run += __shfl_xor(sum_run, 32);
    float inv = 1.f / sum_run;

    u16* ow = lds + 32768 + (wave & 3) * 2048;
    const int shift = wave >> 2;
#pragma unroll
    for (int s_ = 0; s_ < 2; ++s_) {
        if (s_ == 1) __syncthreads();
        if (shift == s_) {
            const int q = l31;
#pragma unroll
            for (int dt = 0; dt < 2; ++dt)
#pragma unroll
                for (int rq = 0; rq < 4; ++rq) {
                    int d = dt * 32 + rq * 8 + 4 * lh;
                    u32 w0 = pk2(oacc[dt][rq * 4 + 0] * inv, oacc[dt][rq * 4 + 1] * inv);
                    u32 w1 = pk2(oacc[dt][rq * 4 + 2] * inv, oacc[dt][rq * 4 + 3] * inv);
                    int byte = q * 128 + ((d * 2) ^ ((q & 7) << 4));
                    *(u32*)((char*)ow + byte) = w0;
                    *(u32*)((char*)ow + byte + 4) = w1;
                }
#pragma unroll
            for (int i = 0; i < 4; ++i) {
                int qq = (lane >> 3) + i * 8;
                int byte = qq * 128 + (((lane & 7) * 16) ^ ((qq & 7) << 4));
                bf16x8 val = *(const bf16x8*)((char*)ow + byte);
                *(bf16x8*)(O + (q0 + qq) * 512 + h * 64 + (lane & 7) * 8) = val;
            }
        }
    }
}

// ---------------------------------------------------------------------------
// GroupNorm stats, coalesced two-stage (verified R6-R13).
// ---------------------------------------------------------------------------
__global__ __launch_bounds__(256)
void gn_part(const float* __restrict__ x, float* __restrict__ part)
{
    const int b = blockIdx.x, ch = blockIdx.y;
    const float* base = x + ((long)b * 4096 + ch * 64) * 512;
    const int t = threadIdx.x;
    const int c4 = t & 127, r0 = t >> 7;
    float sum = 0.f, sq = 0.f;
    for (int rr = r0; rr < 64; rr += 2) {
        float4 v = *(const float4*)(base + (long)rr * 512 + c4 * 4);
        sum += v.x + v.y + v.z + v.w;
        sq  += v.x * v.x + v.y * v.y + v.z * v.z + v.w * v.w;
    }
    __shared__ float s0[128], s1[128];
    if (t >= 128) { s0[c4] = sum; s1[c4] = sq; }
    __syncthreads();
    if (t < 128) {
        sum += s0[c4]; sq += s1[c4];
        sum += __shfl_down(sum, 2); sum += __shfl_down(sum, 1);
        sq  += __shfl_down(sq, 2);  sq  += __shfl_down(sq, 1);
        if ((t & 3) == 0) {
            int g = t >> 2;
            float* pp = part + (long)(b * 64 + ch) * 64;
            pp[g] = sum; pp[32 + g] = sq;
        }
    }
}

__global__ __launch_bounds__(256)
void gn_coef(const float* __restrict__ part, const float* __restrict__ gscale,
             const float* __restrict__ gbias, float* __restrict__ coefA,
             float* __restrict__ coefD)
{
    const int t = threadIdx.x;
    const int b = t >> 5, g = t & 31;
    float S = 0.f, Q = 0.f;
    for (int ch = 0; ch < 64; ++ch) {
        const float* pp = part + (long)(b * 64 + ch) * 64;
        S += pp[g]; Q += pp[32 + g];
    }
    float mean = S * (1.f / 65536.f);
    float var = Q * (1.f / 65536.f) - mean * mean;
    float rstd = rsqrtf(var + 1e-5f);
#pragma unroll
    for (int cc = 0; cc < 16; ++cc) {
        int c = g * 16 + cc;
        float a = gscale[c] * rstd;
        coefA[b * 512 + c] = a;
        coefD[b * 512 + c] = gbias[c] - mean * a;
    }
}

// f32 -> bf16 bulk convert (n multiple of 8*256)
__global__ __launch_bounds__(256)
void conv_bf16(const float* __restrict__ in, u16* __restrict__ out)
{
    long e = ((long)blockIdx.x * 256 + threadIdx.x) * 8;
    float4 v0 = *(const float4*)(in + e);
    float4 v1 = *(const float4*)(in + e + 4);
    float f[8] = { v0.x, v0.y, v0.z, v0.w, v1.x, v1.y, v1.z, v1.w };
    u32x4 o;
#pragma unroll
    for (int q = 0; q < 4; ++q)
        o[q] = (u32)f2bf(f[q * 2]) | ((u32)f2bf(f[q * 2 + 1]) << 16);
    *(u32x4*)(out + e) = o;
}

// all 4 weight transposes in one launch: z selects matrix (f32 -> bf16)
__global__ __launch_bounds__(256)
void transpose_all(const float* __restrict__ Wq, const float* __restrict__ Wk,
                   const float* __restrict__ Wv, const float* __restrict__ Wo,
                   u16* __restrict__ WqT, u16* __restrict__ WkT,
                   u16* __restrict__ WvT, u16* __restrict__ WoT)
{
    __shared__ u16 t[32][33];
    const int z = blockIdx.z;
    const float* in = (z == 0) ? Wq : (z == 1) ? Wk : (z == 2) ? Wv : Wo;
    u16* out = (z == 0) ? WqT : (z == 1) ? WkT : (z == 2) ? WvT : WoT;
    const int R = (z == 1 || z == 2) ? 768 : 512, C = 512;
    const int r0 = blockIdx.y * 32, c0 = blockIdx.x * 32;
    if (r0 >= R) return;
    int tx = threadIdx.x & 31, ty = threadIdx.x >> 5;
    for (int i = ty; i < 32; i += 8) t[i][tx] = f2bf(in[(long)(r0 + i) * C + c0 + tx]);
    __syncthreads();
    for (int i = ty; i < 32; i += 8) out[(long)(c0 + i) * R + r0 + tx] = t[tx][i];
}

extern "C" void kernel_launch(void* const* d_in, const int* in_sizes, int n_in,
                              void* d_out, int out_size, void* d_ws, size_t ws_size,
                              hipStream_t stream)
{
    const float* x    = (const float*)d_in[0];
    const float* cond = (const float*)d_in[1];
    const float* gsc  = (const float*)d_in[2];
    const float* gbi  = (const float*)d_in[3];
    const float* Wq   = (const float*)d_in[4];
    const float* Wk   = (const float*)d_in[5];
    const float* Wv   = (const float*)d_in[6];
    const float* Wo   = (const float*)d_in[7];
    const float* bo   = (const float*)d_in[8];

    char* ws = (char*)d_ws;
    size_t off = 0;
    auto alloc = [&](size_t bytes) -> void* {
        void* p = ws + off; off += (bytes + 255) & ~(size_t)255; return p;
    };
    u16* WqT    = (u16*)alloc(512 * 512 * 2);
    u16* WkT    = (u16*)alloc(512 * 768 * 2);
    u16* WvT    = (u16*)alloc(512 * 768 * 2);
    u16* WoT    = (u16*)alloc(512 * 512 * 2);
    float* cfA  = (float*)alloc(8 * 512 * 4);
    float* cfD  = (float*)alloc(8 * 512 * 4);
    float* part = (float*)alloc(8 * 64 * 64 * 4);
    u16* condb  = (u16*)alloc(2048l * 768 * 2);
    u16* Ob     = (u16*)alloc(33554432);
    u16* Qb     = (u16*)alloc(33554432);
    u16* Kb     = (u16*)alloc(2048l * 512 * 2);
    u16* Vt     = (u16*)alloc(2097152);

    transpose_all<<<dim3(16, 24, 4), 256, 0, stream>>>(Wq, Wk, Wv, Wo, WqT, WkT, WvT, WoT);
    conv_bf16<<<768, 256, 0, stream>>>(cond, condb);

    gn_part<<<dim3(8, 64), 256, 0, stream>>>(x, part);
    gn_coef<<<1, 256, 0, stream>>>(part, gsc, gbi, cfA, cfD);

    // Q = (GN(x) @ WqT) * 0.125*log2(e)  — GN affine fused into A staging
    gemm_bt<0, false, false, true><<<dim3(256, 4), 256, 0, stream>>>(
        x, WqT, nullptr, Qb, nullptr, nullptr, nullptr, cfA, cfD,
        512, 512, 512, 512, 0.18033688011112042f);
    // K and V in one launch (z=0: K->Kb; z=1: V->Vt transposed per head)
    gemm_bt<3, false, false, false><<<dim3(16, 4, 2), 256, 0, stream>>>(
        condb, WkT, WvT, Kb, Vt, nullptr, nullptr, nullptr, nullptr,
        768, 768, 768, 512, 1.f);

    // fused attention: scores+softmax+PV, writes Ob
    attn_fused<<<dim3(16, 64), 512, 0, stream>>>(Qb, Kb, Vt, Ob);

    // out = x + Ob @ WoT + bo    (32768 x 512 x 512), f32, coalesced epilogue
    gemm_bt<1, true, true, false><<<dim3(256, 4), 256, 0, stream>>>(
        Ob, WoT, nullptr, d_out, nullptr, bo, x, nullptr, nullptr,
        512, 512, 512, 512, 1.f);
}

// Round 15
// 176.716 us; speedup vs baseline: 1.1406x; 1.1399x over previous
//
#include <hip/hip_runtime.h>
#include <hip/hip_bf16.h>

typedef unsigned short u16;
typedef unsigned int u32;
typedef __attribute__((ext_vector_type(8))) __bf16 bf16x8;
typedef __attribute__((ext_vector_type(4))) float f32x4;
typedef __attribute__((ext_vector_type(16))) float f32x16;
typedef __attribute__((ext_vector_type(4))) u32 u32x4;

#define DEVFN static __device__ __forceinline__

DEVFN float bf2f(u16 v) { union { u32 u; float f; } x; x.u = (u32)v << 16; return x.f; }
DEVFN u16 f2bf(float f) {
    union { float f; u32 u; } x; x.f = f;
    u32 r = x.u + 0x7fff + ((x.u >> 16) & 1);
    return (u16)(r >> 16);
}

union BF2 { struct { __bf16 lo, hi; } s; u32 w; };
DEVFN u32 pk2(float a, float b) { BF2 t; t.s.lo = (__bf16)a; t.s.hi = (__bf16)b; return t.w; }

DEVFN void gload_lds16(const u16* g, u16* l) {
    __builtin_amdgcn_global_load_lds((const __attribute__((address_space(1))) u32*)g,
                                     (__attribute__((address_space(3))) u32*)l, 16, 0, 0);
}

// ---------------------------------------------------------------------------
// C = A (M,K) @ B^T (N,K), bf16 in, f32 accum. Tile 128x128, BK=32, 4 waves,
// 2-phase double-buffered LDS (T3 minimum recipe): top-of-iter vmcnt(0)+
// barrier, then issue next-tile stage, then compute current tile.
// 16KB/buffer, 32KB total. [FINAL R11 configuration — best measured total
// 176.9us, reproduced twice. Rejected by within-session A/B: 3-buffer counted
// vmcnt (R9), XCD swizzle + lane-linear restage (R10), coef-LDS (R12),
// per-batch folded weights (R8/R13), depth-2 x-prefetch (R14). Do not re-add
// without fresh within-probe A/B evidence.]
// OUTMODE: 0 = bf16 C; 1 = f32 C via coalesced LDS epilogue (+bias/residual);
// 3 = z-select (z=0: bf16 C->Cv weights B, z=1: Vt->Cv2 weights B2).
// AFF: A is f32, GN affine applied during staging (T14 split: global->reg
// issued with B stage, convert+ds_write after MFMA), packed to bf16.
// ---------------------------------------------------------------------------
template<int OUTMODE, bool BIAS, bool RES, bool AFF>
__global__ __launch_bounds__(256)
void gemm_bt(const void* __restrict__ Av, const u16* __restrict__ B,
             const u16* __restrict__ B2,
             void* __restrict__ Cv, void* __restrict__ Cv2,
             const float* __restrict__ bias, const float* __restrict__ res,
             const float* __restrict__ cfA, const float* __restrict__ cfD,
             int K, int lda, int ldb, int ldc, float scale)
{
    __shared__ u16 smem[16384];  // 32KB: [A0 4K | B0 4K | A1 4K | B1 4K] u16
    const int tid = threadIdx.x;
    const int lane = tid & 63, wave = tid >> 6;
    const int wr = wave >> 1, wc = wave & 1;
    const u16* Bsel = (OUTMODE == 3 && blockIdx.z) ? B2 : B;
    const u16* Bb = Bsel + (long)blockIdx.y * 128 * ldb;
    const int ra = tid >> 2, ca = (tid & 3) * 8;       // staging row/col in pass
    const int foff = ((lane & 15) * 4 + (lane >> 4)) * 8;

    f32x4 acc[4][4];
#pragma unroll
    for (int i = 0; i < 4; ++i)
#pragma unroll
        for (int j = 0; j < 4; ++j) acc[i][j] = (f32x4){0.f, 0.f, 0.f, 0.f};

    const int nt = K >> 5;

    auto stageB = [&](int t, u16* bb) {
#pragma unroll
        for (int p = 0; p < 2; ++p)
            gload_lds16(Bb + (long)(p * 64 + ra) * ldb + t * 32 + ca,
                        bb + (p * 256 + tid) * 8);
    };
    const u16* Ab = (const u16*)Av + (long)blockIdx.x * 128 * lda;
    auto stageA = [&](int t, u16* ab) {
#pragma unroll
        for (int p = 0; p < 2; ++p)
            gload_lds16(Ab + (long)(p * 64 + ra) * lda + t * 32 + ca,
                        ab + (p * 256 + tid) * 8);
    };
    const float* xf = (const float*)Av;
    float4 xr[2][2], ar[2][2], dr[2][2];
    auto affLoad = [&](int t) {
#pragma unroll
        for (int p = 0; p < 2; ++p) {
            long m = (long)blockIdx.x * 128 + p * 64 + ra;
            int c = t * 32 + ca;
            const float* src = xf + m * lda + c;
            xr[p][0] = *(const float4*)(src);
            xr[p][1] = *(const float4*)(src + 4);
            int cb = (int)((m >> 12) << 9) + c;
            ar[p][0] = *(const float4*)(cfA + cb);
            ar[p][1] = *(const float4*)(cfA + cb + 4);
            dr[p][0] = *(const float4*)(cfD + cb);
            dr[p][1] = *(const float4*)(cfD + cb + 4);
        }
    };
    auto affWrite = [&](u16* ab) {
#pragma unroll
        for (int p = 0; p < 2; ++p) {
            u32x4 o;
            o[0] = pk2(xr[p][0].x * ar[p][0].x + dr[p][0].x,
                       xr[p][0].y * ar[p][0].y + dr[p][0].y);
            o[1] = pk2(xr[p][0].z * ar[p][0].z + dr[p][0].z,
                       xr[p][0].w * ar[p][0].w + dr[p][0].w);
            o[2] = pk2(xr[p][1].x * ar[p][1].x + dr[p][1].x,
                       xr[p][1].y * ar[p][1].y + dr[p][1].y);
            o[3] = pk2(xr[p][1].z * ar[p][1].z + dr[p][1].z,
                       xr[p][1].w * ar[p][1].w + dr[p][1].w);
            *(u32x4*)(ab + (p * 256 + tid) * 8) = o;
        }
    };

    // ---- prologue: stage tile 0 into buffer 0
    stageB(0, smem + 4096);
    if constexpr (AFF) { affLoad(0); affWrite(smem); }
    else               stageA(0, smem);

    int cur = 0;
    for (int t = 0; t < nt; ++t) {
        asm volatile("s_waitcnt vmcnt(0)" ::: "memory");
        __syncthreads();                       // buf[cur] ready for all waves
        const int nxt = cur ^ 1;
        u16* cA = smem + cur * 8192;
        u16* cB = smem + cur * 8192 + 4096;
        u16* nA = smem + nxt * 8192;
        u16* nB = smem + nxt * 8192 + 4096;
        const bool more = (t + 1 < nt);
        if (more) {                            // issue next-tile stage first
            stageB(t + 1, nB);
            if constexpr (AFF) affLoad(t + 1);
            else               stageA(t + 1, nA);
        }
        bf16x8 av[4], bv[4];
#pragma unroll
        for (int i = 0; i < 4; ++i) av[i] = *(const bf16x8*)(cA + (wr * 4 + i) * 512 + foff);
#pragma unroll
        for (int j = 0; j < 4; ++j) bv[j] = *(const bf16x8*)(cB + (wc * 4 + j) * 512 + foff);
        __builtin_amdgcn_s_setprio(1);
#pragma unroll
        for (int i = 0; i < 4; ++i)
#pragma unroll
            for (int j = 0; j < 4; ++j)
                acc[i][j] = __builtin_amdgcn_mfma_f32_16x16x32_bf16(av[i], bv[j], acc[i][j], 0, 0, 0);
        __builtin_amdgcn_s_setprio(0);
        if (more) { if constexpr (AFF) affWrite(nA); }  // write-late (T14)
        cur = nxt;
    }

    const int m0 = blockIdx.x * 128 + wr * 64 + (lane >> 4) * 4;
    const int n0 = blockIdx.y * 128 + wc * 64 + (lane & 15);
    if constexpr (OUTMODE == 0) {
        u16* Cb = (u16*)Cv;
#pragma unroll
        for (int i = 0; i < 4; ++i)
#pragma unroll
            for (int j = 0; j < 4; ++j) {
                int n = n0 + j * 16;
#pragma unroll
                for (int r = 0; r < 4; ++r) {
                    int m = m0 + i * 16 + r;
                    Cb[(long)m * ldc + n] = f2bf(acc[i][j][r] * scale);
                }
            }
    } else if constexpr (OUTMODE == 1) {
        // coalesced f32 epilogue through padded LDS (32 x 132), 4 row-chunks
        float* cl = (float*)smem;
        float* Co = (float*)Cv;
#pragma unroll
        for (int i = 0; i < 4; ++i) {
            __syncthreads();
#pragma unroll
            for (int j = 0; j < 4; ++j)
#pragma unroll
                for (int r = 0; r < 4; ++r) {
                    int rl = wr * 16 + (lane >> 4) * 4 + r;
                    int col = wc * 64 + j * 16 + (lane & 15);
                    cl[rl * 132 + col] = acc[i][j][r];
                }
            __syncthreads();
            int rl = tid >> 3;
            int c0 = (tid & 7) * 16;
            long m = (long)blockIdx.x * 128 + i * 16 + (rl & 15) + (rl >> 4) * 64;
            long n = (long)blockIdx.y * 128 + c0;
#pragma unroll
            for (int q = 0; q < 4; ++q) {
                float4 v = *(float4*)(cl + rl * 132 + c0 + q * 4);
                float4 o;
                o.x = v.x * scale; o.y = v.y * scale;
                o.z = v.z * scale; o.w = v.w * scale;
                if constexpr (BIAS) {
                    float4 b4 = *(const float4*)(bias + n + q * 4);
                    o.x += b4.x; o.y += b4.y; o.z += b4.z; o.w += b4.w;
                }
                if constexpr (RES) {
                    float4 r4 = *(const float4*)(res + m * ldc + n + q * 4);
                    o.x += r4.x; o.y += r4.y; o.z += r4.z; o.w += r4.w;
                }
                *(float4*)(Co + m * ldc + n + q * 4) = o;
            }
        }
    } else {  // OUTMODE == 3: z=0 bf16 C -> Cv; z=1 Vt -> Cv2
        if (blockIdx.z == 0) {
            u16* Cb = (u16*)Cv;
#pragma unroll
            for (int i = 0; i < 4; ++i)
#pragma unroll
                for (int j = 0; j < 4; ++j) {
                    int n = n0 + j * 16;
#pragma unroll
                    for (int r = 0; r < 4; ++r) {
                        int m = m0 + i * 16 + r;
                        Cb[(long)m * ldc + n] = f2bf(acc[i][j][r] * scale);
                    }
                }
        } else {
#pragma unroll
            for (int i = 0; i < 4; ++i) {
                int m = m0 + i * 16;
                int b = m >> 8, s = m & 255;
#pragma unroll
                for (int j = 0; j < 4; ++j) {
                    int n = n0 + j * 16;
                    int h = n >> 6, d = n & 63;
                    ushort4 pk;
                    pk.x = f2bf(acc[i][j][0]); pk.y = f2bf(acc[i][j][1]);
                    pk.z = f2bf(acc[i][j][2]); pk.w = f2bf(acc[i][j][3]);
                    *(ushort4*)((u16*)Cv2 + (((long)(b * 8 + h) * 64 + d) * 256 + s)) = pk;
                }
            }
        }
    }
}

// ---------------------------------------------------------------------------
// Fused attention v3 (unchanged, verified R5-R14): LDS-staged K/V + online
// softmax. grid (16, 64), 512 threads = 8 waves x 32 queries.
// ---------------------------------------------------------------------------
union U8 { u32 w[4]; bf16x8 v; };

__global__ __launch_bounds__(512, 4)
void attn_fused(const u16* __restrict__ Q, const u16* __restrict__ K,
                const u16* __restrict__ Vt, u16* __restrict__ O)
{
    __shared__ u16 lds[40960];  // 80KB
    const int tid = threadIdx.x, lane = tid & 63, wave = tid >> 6;
    const int bh = blockIdx.y, b = bh >> 3, h = bh & 7;
    const int l31 = lane & 31, lh = lane >> 5;
    const long q0 = (long)b * 4096 + blockIdx.x * 256 + wave * 32;
    const bool hiHalf = (lh != 0);

    {
        const u16* Kb_ = K + (long)b * 256 * 512 + h * 64;
        const u16* Vb_ = Vt + (long)bh * 16384;
#pragma unroll
        for (int it = 0; it < 4; ++it) {
            int f = it * 8 + wave;           // 0..31
            int st = f >> 2, kc = f & 3;
            gload_lds16(Kb_ + (long)(st * 32 + l31) * 512 + kc * 16 + lh * 8,
                        lds + f * 512 + lane * 8);
            int dt = f >> 4, ks = f & 15;
            gload_lds16(Vb_ + (long)(dt * 32 + l31) * 256 + ks * 16 + lh * 8,
                        lds + 16384 + f * 512 + lane * 8);
        }
    }
    bf16x8 qf[4];
    {
        const u16* Qp = Q + (q0 + l31) * 512 + h * 64 + lh * 8;
#pragma unroll
        for (int kc = 0; kc < 4; ++kc) qf[kc] = *(const bf16x8*)(Qp + kc * 16);
    }
    asm volatile("s_waitcnt vmcnt(0)" ::: "memory");
    __syncthreads();

    f32x16 oacc[2];
#pragma unroll
    for (int dt = 0; dt < 2; ++dt)
#pragma unroll
        for (int r = 0; r < 16; ++r) oacc[dt][r] = 0.f;
    float m_run = -3e38f, sum_run = 0.f;

#pragma unroll
    for (int st = 0; st < 8; ++st) {
        f32x16 sc;
#pragma unroll
        for (int r = 0; r < 16; ++r) sc[r] = 0.f;
        __builtin_amdgcn_s_setprio(1);
#pragma unroll
        for (int kc = 0; kc < 4; ++kc) {
            bf16x8 af = *(const bf16x8*)(lds + (st * 4 + kc) * 512 + lane * 8);
            sc = __builtin_amdgcn_mfma_f32_32x32x16_bf16(af, qf[kc], sc, 0, 0, 0);
        }
        __builtin_amdgcn_s_setprio(0);
        float tm = sc[0];
#pragma unroll
        for (int r = 1; r < 16; ++r) tm = fmaxf(tm, sc[r]);
        tm = fmaxf(tm, __shfl_xor(tm, 32));
        if (!__all(tm <= m_run + 8.f)) {
            float mnew = fmaxf(m_run, tm);
            float fac = exp2f(m_run - mnew);
            m_run = mnew;
            sum_run *= fac;
#pragma unroll
            for (int dt = 0; dt < 2; ++dt)
#pragma unroll
                for (int r = 0; r < 16; ++r) oacc[dt][r] *= fac;
        }
#pragma unroll
        for (int r = 0; r < 16; ++r) {
            float e = exp2f(sc[r] - m_run);
            sc[r] = e; sum_run += e;
        }
        u32 c[8], x[8];
#pragma unroll
        for (int i = 0; i < 8; ++i) c[i] = pk2(sc[2 * i], sc[2 * i + 1]);
#pragma unroll
        for (int i = 0; i < 8; ++i) x[i] = (u32)__shfl_xor((int)c[i], 32);
        U8 p0, p1;
        p0.w[0] = hiHalf ? x[2] : c[0];  p0.w[1] = hiHalf ? x[3] : c[1];
        p0.w[2] = hiHalf ? c[2] : x[0];  p0.w[3] = hiHalf ? c[3] : x[1];
        p1.w[0] = hiHalf ? x[6] : c[4];  p1.w[1] = hiHalf ? x[7] : c[5];
        p1.w[2] = hiHalf ? c[6] : x[4];  p1.w[3] = hiHalf ? c[7] : x[5];
        __builtin_amdgcn_s_setprio(1);
#pragma unroll
        for (int dt = 0; dt < 2; ++dt) {
            bf16x8 v0 = *(const bf16x8*)(lds + 16384 + (dt * 16 + st * 2) * 512 + lane * 8);
            bf16x8 v1 = *(const bf16x8*)(lds + 16384 + (dt * 16 + st * 2 + 1) * 512 + lane * 8);
            oacc[dt] = __builtin_amdgcn_mfma_f32_32x32x16_bf16(v0, p0.v, oacc[dt], 0, 0, 0);
            oacc[dt] = __builtin_amdgcn_mfma_f32_32x32x16_bf16(v1, p1.v, oacc[dt], 0, 0, 0);
        }
        __builtin_amdgcn_s_setprio(0);
    }

    sum_run += __shfl_xor(sum_run, 32);
    float inv = 1.f / sum_run;

    u16* ow = lds + 32768 + (wave & 3) * 2048;
    const int shift = wave >> 2;
#pragma unroll
    for (int s_ = 0; s_ < 2; ++s_) {
        if (s_ == 1) __syncthreads();
        if (shift == s_) {
            const int q = l31;
#pragma unroll
            for (int dt = 0; dt < 2; ++dt)
#pragma unroll
                for (int rq = 0; rq < 4; ++rq) {
                    int d = dt * 32 + rq * 8 + 4 * lh;
                    u32 w0 = pk2(oacc[dt][rq * 4 + 0] * inv, oacc[dt][rq * 4 + 1] * inv);
                    u32 w1 = pk2(oacc[dt][rq * 4 + 2] * inv, oacc[dt][rq * 4 + 3] * inv);
                    int byte = q * 128 + ((d * 2) ^ ((q & 7) << 4));
                    *(u32*)((char*)ow + byte) = w0;
                    *(u32*)((char*)ow + byte + 4) = w1;
                }
#pragma unroll
            for (int i = 0; i < 4; ++i) {
                int qq = (lane >> 3) + i * 8;
                int byte = qq * 128 + (((lane & 7) * 16) ^ ((qq & 7) << 4));
                bf16x8 val = *(const bf16x8*)((char*)ow + byte);
                *(bf16x8*)(O + (q0 + qq) * 512 + h * 64 + (lane & 7) * 8) = val;
            }
        }
    }
}

// ---------------------------------------------------------------------------
// GroupNorm stats, coalesced two-stage (verified R6-R14).
// ---------------------------------------------------------------------------
__global__ __launch_bounds__(256)
void gn_part(const float* __restrict__ x, float* __restrict__ part)
{
    const int b = blockIdx.x, ch = blockIdx.y;
    const float* base = x + ((long)b * 4096 + ch * 64) * 512;
    const int t = threadIdx.x;
    const int c4 = t & 127, r0 = t >> 7;
    float sum = 0.f, sq = 0.f;
    for (int rr = r0; rr < 64; rr += 2) {
        float4 v = *(const float4*)(base + (long)rr * 512 + c4 * 4);
        sum += v.x + v.y + v.z + v.w;
        sq  += v.x * v.x + v.y * v.y + v.z * v.z + v.w * v.w;
    }
    __shared__ float s0[128], s1[128];
    if (t >= 128) { s0[c4] = sum; s1[c4] = sq; }
    __syncthreads();
    if (t < 128) {
        sum += s0[c4]; sq += s1[c4];
        sum += __shfl_down(sum, 2); sum += __shfl_down(sum, 1);
        sq  += __shfl_down(sq, 2);  sq  += __shfl_down(sq, 1);
        if ((t & 3) == 0) {
            int g = t >> 2;
            float* pp = part + (long)(b * 64 + ch) * 64;
            pp[g] = sum; pp[32 + g] = sq;
        }
    }
}

__global__ __launch_bounds__(256)
void gn_coef(const float* __restrict__ part, const float* __restrict__ gscale,
             const float* __restrict__ gbias, float* __restrict__ coefA,
             float* __restrict__ coefD)
{
    const int t = threadIdx.x;
    const int b = t >> 5, g = t & 31;
    float S = 0.f, Q = 0.f;
    for (int ch = 0; ch < 64; ++ch) {
        const float* pp = part + (long)(b * 64 + ch) * 64;
        S += pp[g]; Q += pp[32 + g];
    }
    float mean = S * (1.f / 65536.f);
    float var = Q * (1.f / 65536.f) - mean * mean;
    float rstd = rsqrtf(var + 1e-5f);
#pragma unroll
    for (int cc = 0; cc < 16; ++cc) {
        int c = g * 16 + cc;
        float a = gscale[c] * rstd;
        coefA[b * 512 + c] = a;
        coefD[b * 512 + c] = gbias[c] - mean * a;
    }
}

// f32 -> bf16 bulk convert (n multiple of 8*256)
__global__ __launch_bounds__(256)
void conv_bf16(const float* __restrict__ in, u16* __restrict__ out)
{
    long e = ((long)blockIdx.x * 256 + threadIdx.x) * 8;
    float4 v0 = *(const float4*)(in + e);
    float4 v1 = *(const float4*)(in + e + 4);
    float f[8] = { v0.x, v0.y, v0.z, v0.w, v1.x, v1.y, v1.z, v1.w };
    u32x4 o;
#pragma unroll
    for (int q = 0; q < 4; ++q)
        o[q] = (u32)f2bf(f[q * 2]) | ((u32)f2bf(f[q * 2 + 1]) << 16);
    *(u32x4*)(out + e) = o;
}

// all 4 weight transposes in one launch: z selects matrix (f32 -> bf16)
__global__ __launch_bounds__(256)
void transpose_all(const float* __restrict__ Wq, const float* __restrict__ Wk,
                   const float* __restrict__ Wv, const float* __restrict__ Wo,
                   u16* __restrict__ WqT, u16* __restrict__ WkT,
                   u16* __restrict__ WvT, u16* __restrict__ WoT)
{
    __shared__ u16 t[32][33];
    const int z = blockIdx.z;
    const float* in = (z == 0) ? Wq : (z == 1) ? Wk : (z == 2) ? Wv : Wo;
    u16* out = (z == 0) ? WqT : (z == 1) ? WkT : (z == 2) ? WvT : WoT;
    const int R = (z == 1 || z == 2) ? 768 : 512, C = 512;
    const int r0 = blockIdx.y * 32, c0 = blockIdx.x * 32;
    if (r0 >= R) return;
    int tx = threadIdx.x & 31, ty = threadIdx.x >> 5;
    for (int i = ty; i < 32; i += 8) t[i][tx] = f2bf(in[(long)(r0 + i) * C + c0 + tx]);
    __syncthreads();
    for (int i = ty; i < 32; i += 8) out[(long)(c0 + i) * R + r0 + tx] = t[tx][i];
}

extern "C" void kernel_launch(void* const* d_in, const int* in_sizes, int n_in,
                              void* d_out, int out_size, void* d_ws, size_t ws_size,
                              hipStream_t stream)
{
    const float* x    = (const float*)d_in[0];
    const float* cond = (const float*)d_in[1];
    const float* gsc  = (const float*)d_in[2];
    const float* gbi  = (const float*)d_in[3];
    const float* Wq   = (const float*)d_in[4];
    const float* Wk   = (const float*)d_in[5];
    const float* Wv   = (const float*)d_in[6];
    const float* Wo   = (const float*)d_in[7];
    const float* bo   = (const float*)d_in[8];

    char* ws = (char*)d_ws;
    size_t off = 0;
    auto alloc = [&](size_t bytes) -> void* {
        void* p = ws + off; off += (bytes + 255) & ~(size_t)255; return p;
    };
    u16* WqT    = (u16*)alloc(512 * 512 * 2);
    u16* WkT    = (u16*)alloc(512 * 768 * 2);
    u16* WvT    = (u16*)alloc(512 * 768 * 2);
    u16* WoT    = (u16*)alloc(512 * 512 * 2);
    float* cfA  = (float*)alloc(8 * 512 * 4);
    float* cfD  = (float*)alloc(8 * 512 * 4);
    float* part = (float*)alloc(8 * 64 * 64 * 4);
    u16* condb  = (u16*)alloc(2048l * 768 * 2);
    u16* Ob     = (u16*)alloc(33554432);
    u16* Qb     = (u16*)alloc(33554432);
    u16* Kb     = (u16*)alloc(2048l * 512 * 2);
    u16* Vt     = (u16*)alloc(2097152);

    transpose_all<<<dim3(16, 24, 4), 256, 0, stream>>>(Wq, Wk, Wv, Wo, WqT, WkT, WvT, WoT);
    conv_bf16<<<768, 256, 0, stream>>>(cond, condb);

    gn_part<<<dim3(8, 64), 256, 0, stream>>>(x, part);
    gn_coef<<<1, 256, 0, stream>>>(part, gsc, gbi, cfA, cfD);

    // Q = (GN(x) @ WqT) * 0.125*log2(e)  — GN affine fused into A staging
    gemm_bt<0, false, false, true><<<dim3(256, 4), 256, 0, stream>>>(
        x, WqT, nullptr, Qb, nullptr, nullptr, nullptr, cfA, cfD,
        512, 512, 512, 512, 0.18033688011112042f);
    // K and V in one launch (z=0: K->Kb; z=1: V->Vt transposed per head)
    gemm_bt<3, false, false, false><<<dim3(16, 4, 2), 256, 0, stream>>>(
        condb, WkT, WvT, Kb, Vt, nullptr, nullptr, nullptr, nullptr,
        768, 768, 768, 512, 1.f);

    // fused attention: scores+softmax+PV, writes Ob
    attn_fused<<<dim3(16, 64), 512, 0, stream>>>(Qb, Kb, Vt, Ob);

    // out = x + Ob @ WoT + bo    (32768 x 512 x 512), f32, coalesced epilogue
    gemm_bt<1, true, true, false><<<dim3(256, 4), 256, 0, stream>>>(
        Ob, WoT, nullptr, d_out, nullptr, bo, x, nullptr, nullptr,
        512, 512, 512, 512, 1.f);
}